// Round 23
// baseline (263.753 us; speedup 1.0000x reference)
//
#include <hip/hip_runtime.h>
#include <hip/hip_fp16.h>
#include <math.h>

constexpr int D = 64;
constexpr int CAP = 48;        // max slots per row; degrees ~Poisson(10), P(deg>48) ~ 1e-13
constexpr int RPB = 256;       // rows per bucket (shift = 8)
constexpr int EPB = 8192;      // edges per phase-A block (16 per thread x 512 threads)

typedef _Float16 half2_t __attribute__((ext_vector_type(2)));
typedef _Float16 f16x8 __attribute__((ext_vector_type(8)));
typedef float f32x4 __attribute__((ext_vector_type(4)));

__device__ inline unsigned pack2(float lo, float hi){
    __half2 h = __floats2half2_rn(lo, hi);
    return *(unsigned*)&h;
}

// load 16 consecutive u32 from LDS as 4x ds_read_b128 -> statically-indexed regs
__device__ inline void ld16u(const unsigned* base, unsigned* w){
    const uint4* p = (const uint4*)base;
    uint4 a = p[0], b = p[1], c = p[2], d = p[3];
    w[0]=a.x;  w[1]=a.y;  w[2]=a.z;  w[3]=a.w;
    w[4]=b.x;  w[5]=b.y;  w[6]=b.z;  w[7]=b.w;
    w[8]=c.x;  w[9]=c.y;  w[10]=c.z; w[11]=c.w;
    w[12]=d.x; w[13]=d.y; w[14]=d.z; w[15]=d.w;
}

// f32 += dot(half2, half2) with f32 accumulate (v_dot2_f32_f16)
__device__ inline float fdot2(unsigned a, unsigned b, float c){
    return __builtin_amdgcn_fdot2(__builtin_bit_cast(half2_t, a),
                                  __builtin_bit_cast(half2_t, b), c, false);
}

// store 8 fp32 -> 8 fp16 (16 B) at dst
__device__ inline void store_half8(__half* dst, const float* o){
    uint4 w;
    w.x = pack2(o[0], o[1]); w.y = pack2(o[2], o[3]);
    w.z = pack2(o[4], o[5]); w.w = pack2(o[6], o[7]);
    *((uint4*)dst) = w;
}

// load 8 fp16 (16 B) -> 8 fp32
__device__ inline void load_half8(const __half* src, float* r){
    uint4 w = *((const uint4*)src);
    __half2* h = (__half2*)&w;
    float2 f0 = __half22float2(h[0]);
    float2 f1 = __half22float2(h[1]);
    float2 f2 = __half22float2(h[2]);
    float2 f3 = __half22float2(h[3]);
    r[0] = f0.x; r[1] = f0.y; r[2] = f1.x; r[3] = f1.y;
    r[4] = f2.x; r[5] = f2.y; r[6] = f3.x; r[7] = f3.y;
}

// ================= tiny zero kernel =================

__global__ void k_zero(int* __restrict__ p, int n){
    for (int i = threadIdx.x; i < n; i += 256) p[i] = 0;
}

// ================= Phase A: bucket edges by destination row (+ fused mlp_m, dot2) =================
// 512-thread blocks; edge blocks handle 8192 edges (16/thread, reg-cached).
// row space: [0, NI) = dst interfered (relation s2i), [NI, NI+NS) = dst served (relation i2s)

__global__ void __launch_bounds__(512) k_bucket_mlpm(
        const int* __restrict__ es2i, const int* __restrict__ ei2s, int E, int NI,
        int NBUK, int BSTRIDE,
        int* __restrict__ gcur, unsigned* __restrict__ buckets,
        const float* __restrict__ x,
        const float* __restrict__ wm1, const float* __restrict__ bm1,
        const float* __restrict__ wm2, const float* __restrict__ bm2,
        __half* __restrict__ y, int Nmlp, int nbEdge)
{
    __shared__ __align__(16) char smem[8704];
    int t = threadIdx.x;

    if ((int)blockIdx.x < nbEdge){
        int* hist = (int*)smem;            // [1024]
        int* base = (int*)(smem + 4096);   // [1024] — becomes cursor after reserve
        for (int i = t; i < NBUK; i += 512) hist[i] = 0;
        __syncthreads();
        int e0 = blockIdx.x * EPB + t;
        int rr[16], ss[16];
        #pragma unroll
        for (int k = 0; k < 16; k++){
            int i = e0 + k*512;
            if (i < E){
                ss[k] = es2i[i];            rr[k] = es2i[E + i];
            } else if (i < 2*E){
                int j = i - E;
                ss[k] = ei2s[j];            rr[k] = NI + ei2s[E + j];
            } else rr[k] = -1;
        }
        #pragma unroll
        for (int k = 0; k < 16; k++)
            if (rr[k] >= 0) atomicAdd(&hist[rr[k] >> 8], 1);
        __syncthreads();
        for (int b = t; b < NBUK; b += 512){
            int h = hist[b];
            base[b] = h ? atomicAdd(&gcur[b], h) : 0;
        }
        __syncthreads();
        #pragma unroll
        for (int k = 0; k < 16; k++){
            if (rr[k] >= 0){
                int b = rr[k] >> 8;
                int p = atomicAdd(&base[b], 1);
                if (p < BSTRIDE)
                    buckets[(size_t)b*BSTRIDE + p] =
                        ((unsigned)(rr[k] & 255) << 24) | (unsigned)ss[k];
            }
        }
        return;
    }

    // ---- message MLP: y = mlp_m(x), dot2 packed weights, b128 reads ----
    unsigned* w1p = (unsigned*)smem;            // [32 kp][32 j]  4 KB
    unsigned* w2p = (unsigned*)(smem + 4096);   // [16 jp][64 c]  4 KB
    float*    sb1 = (float*)(smem + 8192);      // [32]
    float*    sb2 = (float*)(smem + 8320);      // [64]
    for (int i = t; i < 1024; i += 512){ int kp=i>>5, j=i&31; w1p[i]=pack2(wm1[(2*kp)*32+j], wm1[(2*kp+1)*32+j]); }
    for (int i = t; i < 1024; i += 512){ int jp=i>>6, c=i&63; w2p[i]=pack2(wm2[(2*jp)*64+c], wm2[(2*jp+1)*64+c]); }
    if (t < 32) sb1[t] = bm1[t];
    else if (t >= 64 && t < 128) sb2[t - 64] = bm2[t - 64];
    __syncthreads();
    int n = ((int)blockIdx.x - nbEdge)*512 + t;
    if (n >= Nmlp) return;

    const float4* xp = (const float4*)(x + (size_t)n*D);
    unsigned xq[32];
    #pragma unroll
    for (int i = 0; i < 16; i++){
        float4 v = xp[i];
        xq[2*i]   = pack2(v.x, v.y);
        xq[2*i+1] = pack2(v.z, v.w);
    }
    float h[32];
    #pragma unroll
    for (int j = 0; j < 32; j++) h[j] = 0.f;
    #pragma unroll
    for (int kp = 0; kp < 32; kp++){
        unsigned xv = xq[kp];
        unsigned w[32];
        ld16u(&w1p[kp*32],      w);
        ld16u(&w1p[kp*32 + 16], w + 16);
        #pragma unroll
        for (int j = 0; j < 32; j++) h[j] = fdot2(xv, w[j], h[j]);
    }
    #pragma unroll
    for (int j = 0; j < 32; j++) h[j] = fmaxf(h[j] + sb1[j], 0.f);
    unsigned hh[16];
    #pragma unroll
    for (int jp = 0; jp < 16; jp++) hh[jp] = pack2(h[2*jp], h[2*jp+1]);

    __half* yrow = y + (size_t)n*D;
    #pragma unroll
    for (int c0 = 0; c0 < 64; c0 += 32){
        float o[32];
        #pragma unroll
        for (int c = 0; c < 32; c++) o[c] = sb2[c0 + c];
        #pragma unroll
        for (int jp = 0; jp < 16; jp++){
            unsigned hv = hh[jp];
            unsigned w[32];
            ld16u(&w2p[jp*64 + c0],      w);
            ld16u(&w2p[jp*64 + c0 + 16], w + 16);
            #pragma unroll
            for (int c = 0; c < 32; c++) o[c] = fdot2(hv, w[c], o[c]);
        }
        #pragma unroll
        for (int c = 0; c < 32; c++) o[c] = fmaxf(o[c], 0.f);
        store_half8(yrow + c0,      &o[0]);
        store_half8(yrow + c0 + 8,  &o[8]);
        store_half8(yrow + c0 + 16, &o[16]);
        store_half8(yrow + c0 + 24, &o[24]);
    }
}

// ================= Phase B: LDS-assembled scatter, one block per bucket =================

__global__ void __launch_bounds__(512) k_scatter_lds(const int* __restrict__ gcur,
        const unsigned* __restrict__ buckets, int BSTRIDE, int NTOT,
        int* __restrict__ cnt, int* __restrict__ slots)
{
    __shared__ int lcnt[RPB];
    __shared__ int lslots[RPB*CAP];    // 48 KB
    int t = threadIdx.x;
    int b = blockIdx.x;
    int r0 = b * RPB;
    int nrows = NTOT - r0; if (nrows > RPB) nrows = RPB;

    for (int i = t; i < RPB; i += 512) lcnt[i] = 0;
    __syncthreads();

    int n = gcur[b]; if (n > BSTRIDE) n = BSTRIDE;
    const unsigned* bp = buckets + (size_t)b*BSTRIDE;
    for (int k = t; k < n; k += 512){
        unsigned e = bp[k];
        int lr  = e >> 24;
        int src = e & 0xFFFFFF;
        int pos = atomicAdd(&lcnt[lr], 1);
        if (pos < CAP) lslots[lr*CAP + pos] = src;
    }
    __syncthreads();

    int4* gs = (int4*)(slots + (size_t)r0*CAP);
    const int4* ls = (const int4*)lslots;
    int n4 = nrows*CAP/4;
    for (int i = t; i < n4; i += 512) gs[i] = ls[i];
    for (int i = t; i < nrows; i += 512) cnt[r0 + i] = lcnt[i];
}

// ================= fused gather + update-MLP + message-MLP via MFMA =================
// 4 waves/block x 2 tiles (block covers 128 nodes). Per tile, wave = 16 nodes.
// Gather: lane l -> node (l&15), column quarter (l>>4): reads 32 B of each
// neighbor row; each lane owns distinct columns (no cross-lane reduce).
// Result staged in LDS, feeding the MFMA A-fragments directly.
// A-frag: row = l&15, k = 8*(l>>4)+i.  D-frag: col = l&15, row = 4*(l>>4)+r.

__global__ void __launch_bounds__(256) k_conv_um(const __half* __restrict__ Msrc,
        const int* __restrict__ cnt, const int* __restrict__ slots,
        const float* __restrict__ wu1, const float* __restrict__ bu1,
        const float* __restrict__ wu2, const float* __restrict__ bu2,
        const float* __restrict__ wm1, const float* __restrict__ bm1,
        const float* __restrict__ wm2, const float* __restrict__ bm2,
        __half* __restrict__ Mdst, int N)
{
    __shared__ __half lds_x [4][16][72];
    __shared__ float  lds_h [4][16][20];
    __shared__ float  lds_y [4][16][68];
    __shared__ float  lds_hm[4][16][36];
    __shared__ __half lds_m [4][16][72];

    int t  = threadIdx.x;
    int wv = t >> 6, l = t & 63;
    int m  = l & 15, g = l >> 4;

    // ---- B fragments (weights), loaded once per wave ----
    f16x8 Bu1[2], Bu2[4], Bm1[2][2], Bm2[4];
    #pragma unroll
    for (int kt = 0; kt < 2; kt++)
        #pragma unroll
        for (int i = 0; i < 8; i++)
            Bu1[kt][i] = (_Float16)wu1[(kt*32 + 8*g + i)*16 + m];
    #pragma unroll
    for (int jb = 0; jb < 4; jb++)
        #pragma unroll
        for (int i = 0; i < 8; i++){
            int k = 8*g + i;
            Bu2[jb][i] = (k < 16) ? (_Float16)wu2[k*64 + jb*16 + m] : (_Float16)0.f;
        }
    #pragma unroll
    for (int kt = 0; kt < 2; kt++)
        #pragma unroll
        for (int nt = 0; nt < 2; nt++)
            #pragma unroll
            for (int i = 0; i < 8; i++)
                Bm1[kt][nt][i] = (_Float16)wm1[(kt*32 + 8*g + i)*32 + nt*16 + m];
    #pragma unroll
    for (int jb = 0; jb < 4; jb++)
        #pragma unroll
        for (int i = 0; i < 8; i++)
            Bm2[jb][i] = (_Float16)wm2[(8*g + i)*64 + jb*16 + m];

    float bu1v = bu1[m];
    float bu2v[4], bm2v[4], bm1v[2];
    #pragma unroll
    for (int jb = 0; jb < 4; jb++){ bu2v[jb] = bu2[jb*16 + m]; bm2v[jb] = bm2[jb*16 + m]; }
    #pragma unroll
    for (int nt = 0; nt < 2; nt++) bm1v[nt] = bm1[nt*16 + m];

    #pragma unroll
    for (int tile = 0; tile < 2; tile++){
        int nb = blockIdx.x*128 + tile*64 + wv*16;
        if (nb >= N) break;

        // ---- gather: node = nb+m, columns [g*16, g*16+16) ----
        float acc[16];
        #pragma unroll
        for (int i = 0; i < 16; i++) acc[i] = 0.f;
        int node = nb + m;
        if (node < N){
            int deg = cnt[node]; deg = deg < CAP ? deg : CAP;
            const int* row = slots + (size_t)node*CAP;
            for (int k = 0; k < deg; k++){
                int s = row[k];
                const __half* mr = Msrc + (size_t)s*64 + g*16;
                float v[16];
                load_half8(mr,     v);
                load_half8(mr + 8, v + 8);
                #pragma unroll
                for (int i = 0; i < 16; i++) acc[i] += v[i];
            }
        }
        store_half8(&lds_x[wv][m][g*16],     acc);
        store_half8(&lds_x[wv][m][g*16 + 8], acc + 8);

        // ---- A_x from LDS (same wave wrote it; DS ops program-ordered) ----
        f16x8 Ax0 = *reinterpret_cast<const f16x8*>(&lds_x[wv][m][8*g]);
        f16x8 Ax1 = *reinterpret_cast<const f16x8*>(&lds_x[wv][m][32 + 8*g]);

        // u1
        f32x4 a1 = {0.f, 0.f, 0.f, 0.f};
        a1 = __builtin_amdgcn_mfma_f32_16x16x32_f16(Ax0, Bu1[0], a1, 0, 0, 0);
        a1 = __builtin_amdgcn_mfma_f32_16x16x32_f16(Ax1, Bu1[1], a1, 0, 0, 0);
        #pragma unroll
        for (int r = 0; r < 4; r++)
            lds_h[wv][4*g + r][m] = fmaxf(a1[r] + bu1v, 0.f);

        f16x8 Ah;
        #pragma unroll
        for (int i = 0; i < 8; i++){
            int k = 8*g + i;
            Ah[i] = (k < 16) ? (_Float16)lds_h[wv][m][k] : (_Float16)0.f;
        }

        // u2
        #pragma unroll
        for (int jb = 0; jb < 4; jb++){
            f32x4 a2 = {0.f, 0.f, 0.f, 0.f};
            a2 = __builtin_amdgcn_mfma_f32_16x16x32_f16(Ah, Bu2[jb], a2, 0, 0, 0);
            #pragma unroll
            for (int r = 0; r < 4; r++)
                lds_y[wv][4*g + r][jb*16 + m] = fmaxf(a2[r] + bu2v[jb], 0.f);
        }

        f16x8 Ay0, Ay1;
        #pragma unroll
        for (int i = 0; i < 8; i++){
            Ay0[i] = (_Float16)lds_y[wv][m][8*g + i];
            Ay1[i] = (_Float16)lds_y[wv][m][32 + 8*g + i];
        }

        // m1
        #pragma unroll
        for (int nt = 0; nt < 2; nt++){
            f32x4 a3 = {0.f, 0.f, 0.f, 0.f};
            a3 = __builtin_amdgcn_mfma_f32_16x16x32_f16(Ay0, Bm1[0][nt], a3, 0, 0, 0);
            a3 = __builtin_amdgcn_mfma_f32_16x16x32_f16(Ay1, Bm1[1][nt], a3, 0, 0, 0);
            #pragma unroll
            for (int r = 0; r < 4; r++)
                lds_hm[wv][4*g + r][nt*16 + m] = fmaxf(a3[r] + bm1v[nt], 0.f);
        }

        f16x8 Ahm;
        #pragma unroll
        for (int i = 0; i < 8; i++)
            Ahm[i] = (_Float16)lds_hm[wv][m][8*g + i];

        // m2
        #pragma unroll
        for (int jb = 0; jb < 4; jb++){
            f32x4 a4 = {0.f, 0.f, 0.f, 0.f};
            a4 = __builtin_amdgcn_mfma_f32_16x16x32_f16(Ahm, Bm2[jb], a4, 0, 0, 0);
            #pragma unroll
            for (int r = 0; r < 4; r++)
                lds_m[wv][4*g + r][jb*16 + m] = __float2half(fmaxf(a4[r] + bm2v[jb], 0.f));
        }

        // coalesced writeback: 16 rows x 128 B
        int lr = l >> 2;
        int wnode = nb + lr;
        if (wnode < N){
            uint4* dst = (uint4*)(Mdst + (size_t)wnode*64);
            const uint4* src = (const uint4*)&lds_m[wv][lr][0];
            int c = l & 3;
            dst[c]     = src[c];
            dst[c + 4] = src[c + 4];
        }
    }
}

// ================= fused gather + update-MLP + output head via MFMA =================

__device__ inline float fast_tanh(float x){
    float ax = fabsf(x);
    float e  = __expf(2.f*ax);
    float t  = 1.f - 2.f/(e + 1.f);
    return copysignf(t, x);
}

__global__ void __launch_bounds__(256) k_conv_uo(const __half* __restrict__ Msrc,
        const int* __restrict__ cnt, const int* __restrict__ slots,
        const float* __restrict__ wu1, const float* __restrict__ bu1,
        const float* __restrict__ wu2, const float* __restrict__ bu2,
        const float* __restrict__ wo,  const float* __restrict__ bo,
        float* __restrict__ out, int N)
{
    __shared__ __half lds_x[4][16][72];
    __shared__ float  lds_h[4][16][20];
    __shared__ float  lds_y[4][16][68];
    __shared__ float  lds_o[4][16][68];

    int t  = threadIdx.x;
    int wv = t >> 6, l = t & 63;
    int m  = l & 15, g = l >> 4;

    // ---- B fragments ----
    f16x8 Bu1[2], Bu2[4], Bo[2][4];
    #pragma unroll
    for (int kt = 0; kt < 2; kt++)
        #pragma unroll
        for (int i = 0; i < 8; i++)
            Bu1[kt][i] = (_Float16)wu1[(kt*32 + 8*g + i)*16 + m];
    #pragma unroll
    for (int jb = 0; jb < 4; jb++)
        #pragma unroll
        for (int i = 0; i < 8; i++){
            int k = 8*g + i;
            Bu2[jb][i] = (k < 16) ? (_Float16)wu2[k*64 + jb*16 + m] : (_Float16)0.f;
        }
    #pragma unroll
    for (int kt = 0; kt < 2; kt++)
        #pragma unroll
        for (int jb = 0; jb < 4; jb++)
            #pragma unroll
            for (int i = 0; i < 8; i++)
                Bo[kt][jb][i] = (_Float16)wo[(kt*32 + 8*g + i)*64 + jb*16 + m];

    float bu1v = bu1[m];
    float bu2v[4], bov[4];
    #pragma unroll
    for (int jb = 0; jb < 4; jb++){ bu2v[jb] = bu2[jb*16 + m]; bov[jb] = bo[jb*16 + m]; }

    #pragma unroll
    for (int tile = 0; tile < 2; tile++){
        int nb = blockIdx.x*128 + tile*64 + wv*16;
        if (nb >= N) break;

        // ---- gather ----
        float acc[16];
        #pragma unroll
        for (int i = 0; i < 16; i++) acc[i] = 0.f;
        int node = nb + m;
        if (node < N){
            int deg = cnt[node]; deg = deg < CAP ? deg : CAP;
            const int* row = slots + (size_t)node*CAP;
            for (int k = 0; k < deg; k++){
                int s = row[k];
                const __half* mr = Msrc + (size_t)s*64 + g*16;
                float v[16];
                load_half8(mr,     v);
                load_half8(mr + 8, v + 8);
                #pragma unroll
                for (int i = 0; i < 16; i++) acc[i] += v[i];
            }
        }
        store_half8(&lds_x[wv][m][g*16],     acc);
        store_half8(&lds_x[wv][m][g*16 + 8], acc + 8);

        f16x8 Ax0 = *reinterpret_cast<const f16x8*>(&lds_x[wv][m][8*g]);
        f16x8 Ax1 = *reinterpret_cast<const f16x8*>(&lds_x[wv][m][32 + 8*g]);

        // u1
        f32x4 a1 = {0.f, 0.f, 0.f, 0.f};
        a1 = __builtin_amdgcn_mfma_f32_16x16x32_f16(Ax0, Bu1[0], a1, 0, 0, 0);
        a1 = __builtin_amdgcn_mfma_f32_16x16x32_f16(Ax1, Bu1[1], a1, 0, 0, 0);
        #pragma unroll
        for (int r = 0; r < 4; r++)
            lds_h[wv][4*g + r][m] = fmaxf(a1[r] + bu1v, 0.f);

        f16x8 Ah;
        #pragma unroll
        for (int i = 0; i < 8; i++){
            int k = 8*g + i;
            Ah[i] = (k < 16) ? (_Float16)lds_h[wv][m][k] : (_Float16)0.f;
        }

        // u2
        #pragma unroll
        for (int jb = 0; jb < 4; jb++){
            f32x4 a2 = {0.f, 0.f, 0.f, 0.f};
            a2 = __builtin_amdgcn_mfma_f32_16x16x32_f16(Ah, Bu2[jb], a2, 0, 0, 0);
            #pragma unroll
            for (int r = 0; r < 4; r++)
                lds_y[wv][4*g + r][jb*16 + m] = fmaxf(a2[r] + bu2v[jb], 0.f);
        }

        f16x8 Ay0, Ay1;
        #pragma unroll
        for (int i = 0; i < 8; i++){
            Ay0[i] = (_Float16)lds_y[wv][m][8*g + i];
            Ay1[i] = (_Float16)lds_y[wv][m][32 + 8*g + i];
        }

        // head
        #pragma unroll
        for (int jb = 0; jb < 4; jb++){
            f32x4 a3 = {0.f, 0.f, 0.f, 0.f};
            a3 = __builtin_amdgcn_mfma_f32_16x16x32_f16(Ay0, Bo[0][jb], a3, 0, 0, 0);
            a3 = __builtin_amdgcn_mfma_f32_16x16x32_f16(Ay1, Bo[1][jb], a3, 0, 0, 0);
            #pragma unroll
            for (int r = 0; r < 4; r++)
                lds_o[wv][4*g + r][jb*16 + m] = fast_tanh(a3[r] + bov[jb]);
        }

        // coalesced writeback: 16 rows x 256 B
        int lr = l >> 2;
        int wnode = nb + lr;
        if (wnode < N){
            float4* dst = (float4*)(out + (size_t)wnode*64);
            const float4* src = (const float4*)&lds_o[wv][lr][0];
            int c = l & 3;
            dst[c]      = src[c];
            dst[c + 4]  = src[c + 4];
            dst[c + 8]  = src[c + 8];
            dst[c + 12] = src[c + 12];
        }
    }
}

// ================= launch =================

extern "C" void kernel_launch(void* const* d_in, const int* in_sizes, int n_in,
                              void* d_out, int out_size, void* d_ws, size_t ws_size,
                              hipStream_t stream)
{
    const float* x_interfered = (const float*)d_in[1];
    const int*   e_s2i        = (const int*)d_in[2];
    const int*   e_i2s        = (const int*)d_in[3];
    const float* wm1 = (const float*)d_in[4];  const float* bm1 = (const float*)d_in[5];
    const float* wm2 = (const float*)d_in[6];  const float* bm2 = (const float*)d_in[7];
    const float* wu1 = (const float*)d_in[8];  const float* bu1 = (const float*)d_in[9];
    const float* wu2 = (const float*)d_in[10]; const float* bu2 = (const float*)d_in[11];
    const float* wo  = (const float*)d_in[12]; const float* bo  = (const float*)d_in[13];

    const int NS = in_sizes[0] / D;
    const int NI = in_sizes[1] / D;
    const int E  = in_sizes[2] / 2;
    const int NMAX = (NS > NI) ? NS : NI;
    const int NTOT = NI + NS;   // rows [0,NI)=dst interfered, [NI,NTOT)=dst served

    const int NBUK = ((NTOT - 1) >> 8) + 1;          // RPB=256 rows per bucket
    int avg = (2*E) / NBUK;
    const int BSTRIDE = ((2*avg) + 1023) & ~1023;    // 2x average, safe for Binomial spread

    char* p = (char*)d_ws;
    auto alloc = [&](size_t bytes) -> void* {
        void* r = (void*)p;
        p += (bytes + 255) & ~(size_t)255;
        return r;
    };
    __half*   MA     = (__half*)alloc((size_t)NMAX*D*2);
    __half*   MB     = (__half*)alloc((size_t)NMAX*D*2);
    int*      cnt    = (int*)alloc((size_t)NTOT*4);
    int*      gcur   = (int*)alloc((size_t)NBUK*4);
    int*      slots  = (int*)alloc((size_t)NTOT*CAP*4);
    unsigned* buckets= (unsigned*)alloc((size_t)NBUK*BSTRIDE*4);
    (void)ws_size; (void)n_in; (void)out_size;

    const int* cnt_i = cnt;
    const int* cnt_s = cnt + NI;
    const int* slots_i = slots;
    const int* slots_s = slots + (size_t)NI*CAP;

    // custom zero kernel (graph-capture-safe)
    k_zero<<<1, 256, 0, stream>>>(gcur, NBUK);

    const int nbEdge = (2*E + EPB - 1)/EPB;
    const int nbMlp  = (NI + 511)/512;
    // Phase A: bucket both relations' edges + mlp_m(x_interfered) -> MA (fp16)
    k_bucket_mlpm<<<nbEdge + nbMlp, 512, 0, stream>>>(
        e_s2i, e_i2s, E, NI, NBUK, BSTRIDE, gcur, buckets,
        x_interfered, wm1, bm1, wm2, bm2, MA, NI, nbEdge);
    // Phase B: LDS-assembled scatter, one block per bucket
    k_scatter_lds<<<NBUK, 512, 0, stream>>>(gcur, buckets, BSTRIDE, NTOT, cnt, slots);

    // live chain: i0 -> s1 -> i2 -> s3 -> out  (M double-buffered: fused kernels
    // read Msrc and write Mdst concurrently across blocks)
    // conv1 (i2s): s1 nodes; gather MA via csr_s -> MB
    k_conv_um<<<(NS + 127)/128, 256, 0, stream>>>(MA, cnt_s, slots_s,
        wu1, bu1, wu2, bu2, wm1, bm1, wm2, bm2, MB, NS);
    // conv2 (s2i): i2 nodes; gather MB via csr_i -> MA
    k_conv_um<<<(NI + 127)/128, 256, 0, stream>>>(MB, cnt_i, slots_i,
        wu1, bu1, wu2, bu2, wm1, bm1, wm2, bm2, MA, NI);
    // conv3 (i2s): s3 nodes; gather MA via csr_s -> output head
    k_conv_uo<<<(NS + 127)/128, 256, 0, stream>>>(MA, cnt_s, slots_s,
        wu1, bu1, wu2, bu2, wo, bo, (float*)d_out, NS);
}

// Round 24
// 219.512 us; speedup vs baseline: 1.2015x; 1.2015x over previous
//
#include <hip/hip_runtime.h>
#include <hip/hip_fp16.h>
#include <math.h>

constexpr int D = 64;
constexpr int CAP = 48;        // max slots per row; degrees ~Poisson(10), P(deg>48) ~ 1e-13
constexpr int RPB = 256;       // rows per bucket (shift = 8)
constexpr int EPB = 8192;      // edges per phase-A block (16 per thread x 512 threads)

typedef _Float16 half2_t __attribute__((ext_vector_type(2)));
typedef _Float16 f16x8 __attribute__((ext_vector_type(8)));
typedef float f32x4 __attribute__((ext_vector_type(4)));

// f32 += dot(half2, half2) with f32 accumulate (v_dot2_f32_f16)
__device__ inline float fdot2(unsigned a, unsigned b, float c){
    return __builtin_amdgcn_fdot2(__builtin_bit_cast(half2_t, a),
                                  __builtin_bit_cast(half2_t, b), c, false);
}

__device__ inline unsigned pack2(float lo, float hi){
    __half2 h = __floats2half2_rn(lo, hi);
    return *(unsigned*)&h;
}

// load 16 consecutive u32 from LDS as 4x ds_read_b128 -> statically-indexed regs
__device__ inline void ld16u(const unsigned* base, unsigned* w){
    const uint4* p = (const uint4*)base;
    uint4 a = p[0], b = p[1], c = p[2], d = p[3];
    w[0]=a.x;  w[1]=a.y;  w[2]=a.z;  w[3]=a.w;
    w[4]=b.x;  w[5]=b.y;  w[6]=b.z;  w[7]=b.w;
    w[8]=c.x;  w[9]=c.y;  w[10]=c.z; w[11]=c.w;
    w[12]=d.x; w[13]=d.y; w[14]=d.z; w[15]=d.w;
}

// store 8 fp32 -> 8 fp16 (16 B) at dst
__device__ inline void store_half8(__half* dst, const float* o){
    uint4 w;
    w.x = pack2(o[0], o[1]); w.y = pack2(o[2], o[3]);
    w.z = pack2(o[4], o[5]); w.w = pack2(o[6], o[7]);
    *((uint4*)dst) = w;
}

// load 8 fp16 (16 B) -> 8 fp32
__device__ inline void load_half8(const __half* src, float* r){
    uint4 w = *((const uint4*)src);
    __half2* h = (__half2*)&w;
    float2 f0 = __half22float2(h[0]);
    float2 f1 = __half22float2(h[1]);
    float2 f2 = __half22float2(h[2]);
    float2 f3 = __half22float2(h[3]);
    r[0] = f0.x; r[1] = f0.y; r[2] = f1.x; r[3] = f1.y;
    r[4] = f2.x; r[5] = f2.y; r[6] = f3.x; r[7] = f3.y;
}

// ================= tiny zero kernel (replaces hipMemsetAsync's fill) =================

__global__ void k_zero(int* __restrict__ p, int n){
    for (int i = threadIdx.x; i < n; i += 256) p[i] = 0;
}

// ================= Phase A: bucket edges by destination row (+ fused mlp_m, dot2) =================
// 512-thread blocks; edge blocks handle 8192 edges (16/thread, reg-cached).
// row space: [0, NI) = dst interfered (relation s2i), [NI, NI+NS) = dst served (relation i2s)

__global__ void __launch_bounds__(512) k_bucket_mlpm(
        const int* __restrict__ es2i, const int* __restrict__ ei2s, int E, int NI,
        int NBUK, int BSTRIDE,
        int* __restrict__ gcur, unsigned* __restrict__ buckets,
        const float* __restrict__ x,
        const float* __restrict__ wm1, const float* __restrict__ bm1,
        const float* __restrict__ wm2, const float* __restrict__ bm2,
        __half* __restrict__ y, int Nmlp, int nbEdge)
{
    __shared__ __align__(16) char smem[8704];
    int t = threadIdx.x;

    if ((int)blockIdx.x < nbEdge){
        int* hist = (int*)smem;            // [1024]
        int* base = (int*)(smem + 4096);   // [1024] — becomes cursor after reserve
        for (int i = t; i < NBUK; i += 512) hist[i] = 0;
        __syncthreads();
        int e0 = blockIdx.x * EPB + t;
        int rr[16], ss[16];
        #pragma unroll
        for (int k = 0; k < 16; k++){
            int i = e0 + k*512;
            if (i < E){
                ss[k] = es2i[i];            rr[k] = es2i[E + i];
            } else if (i < 2*E){
                int j = i - E;
                ss[k] = ei2s[j];            rr[k] = NI + ei2s[E + j];
            } else rr[k] = -1;
        }
        #pragma unroll
        for (int k = 0; k < 16; k++)
            if (rr[k] >= 0) atomicAdd(&hist[rr[k] >> 8], 1);
        __syncthreads();
        for (int b = t; b < NBUK; b += 512){
            int h = hist[b];
            base[b] = h ? atomicAdd(&gcur[b], h) : 0;
        }
        __syncthreads();
        #pragma unroll
        for (int k = 0; k < 16; k++){
            if (rr[k] >= 0){
                int b = rr[k] >> 8;
                int p = atomicAdd(&base[b], 1);
                if (p < BSTRIDE)
                    buckets[(size_t)b*BSTRIDE + p] =
                        ((unsigned)(rr[k] & 255) << 24) | (unsigned)ss[k];
            }
        }
        return;
    }

    // ---- message MLP: y = mlp_m(x), dot2 packed weights, b128 reads ----
    unsigned* w1p = (unsigned*)smem;            // [32 kp][32 j]  4 KB
    unsigned* w2p = (unsigned*)(smem + 4096);   // [16 jp][64 c]  4 KB
    float*    sb1 = (float*)(smem + 8192);      // [32]
    float*    sb2 = (float*)(smem + 8320);      // [64]
    for (int i = t; i < 1024; i += 512){ int kp=i>>5, j=i&31; w1p[i]=pack2(wm1[(2*kp)*32+j], wm1[(2*kp+1)*32+j]); }
    for (int i = t; i < 1024; i += 512){ int jp=i>>6, c=i&63; w2p[i]=pack2(wm2[(2*jp)*64+c], wm2[(2*jp+1)*64+c]); }
    if (t < 32) sb1[t] = bm1[t];
    else if (t >= 64 && t < 128) sb2[t - 64] = bm2[t - 64];
    __syncthreads();
    int n = ((int)blockIdx.x - nbEdge)*512 + t;
    if (n >= Nmlp) return;

    const float4* xp = (const float4*)(x + (size_t)n*D);
    unsigned xq[32];
    #pragma unroll
    for (int i = 0; i < 16; i++){
        float4 v = xp[i];
        xq[2*i]   = pack2(v.x, v.y);
        xq[2*i+1] = pack2(v.z, v.w);
    }
    float h[32];
    #pragma unroll
    for (int j = 0; j < 32; j++) h[j] = 0.f;
    #pragma unroll
    for (int kp = 0; kp < 32; kp++){
        unsigned xv = xq[kp];
        unsigned w[32];
        ld16u(&w1p[kp*32],      w);
        ld16u(&w1p[kp*32 + 16], w + 16);
        #pragma unroll
        for (int j = 0; j < 32; j++) h[j] = fdot2(xv, w[j], h[j]);
    }
    #pragma unroll
    for (int j = 0; j < 32; j++) h[j] = fmaxf(h[j] + sb1[j], 0.f);
    unsigned hh[16];
    #pragma unroll
    for (int jp = 0; jp < 16; jp++) hh[jp] = pack2(h[2*jp], h[2*jp+1]);

    __half* yrow = y + (size_t)n*D;
    #pragma unroll
    for (int c0 = 0; c0 < 64; c0 += 32){
        float o[32];
        #pragma unroll
        for (int c = 0; c < 32; c++) o[c] = sb2[c0 + c];
        #pragma unroll
        for (int jp = 0; jp < 16; jp++){
            unsigned hv = hh[jp];
            unsigned w[32];
            ld16u(&w2p[jp*64 + c0],      w);
            ld16u(&w2p[jp*64 + c0 + 16], w + 16);
            #pragma unroll
            for (int c = 0; c < 32; c++) o[c] = fdot2(hv, w[c], o[c]);
        }
        #pragma unroll
        for (int c = 0; c < 32; c++) o[c] = fmaxf(o[c], 0.f);
        store_half8(yrow + c0,      &o[0]);
        store_half8(yrow + c0 + 8,  &o[8]);
        store_half8(yrow + c0 + 16, &o[16]);
        store_half8(yrow + c0 + 24, &o[24]);
    }
}

// ================= Phase B: LDS-assembled scatter, one block per bucket =================

__global__ void __launch_bounds__(512) k_scatter_lds(const int* __restrict__ gcur,
        const unsigned* __restrict__ buckets, int BSTRIDE, int NTOT,
        int* __restrict__ cnt, int* __restrict__ slots)
{
    __shared__ int lcnt[RPB];
    __shared__ int lslots[RPB*CAP];    // 48 KB
    int t = threadIdx.x;
    int b = blockIdx.x;
    int r0 = b * RPB;
    int nrows = NTOT - r0; if (nrows > RPB) nrows = RPB;

    for (int i = t; i < RPB; i += 512) lcnt[i] = 0;
    __syncthreads();

    int n = gcur[b]; if (n > BSTRIDE) n = BSTRIDE;
    const unsigned* bp = buckets + (size_t)b*BSTRIDE;
    for (int k = t; k < n; k += 512){
        unsigned e = bp[k];
        int lr  = e >> 24;
        int src = e & 0xFFFFFF;
        int pos = atomicAdd(&lcnt[lr], 1);
        if (pos < CAP) lslots[lr*CAP + pos] = src;
    }
    __syncthreads();

    int4* gs = (int4*)(slots + (size_t)r0*CAP);
    const int4* ls = (const int4*)lslots;
    int n4 = nrows*CAP/4;
    for (int i = t; i < n4; i += 512) gs[i] = ls[i];
    for (int i = t; i < nrows; i += 512) cnt[r0 + i] = lcnt[i];
}

// ================= gather-aggregation: wave per node, 8 edges x 8 lanes x uint4 =================

__global__ void __launch_bounds__(256) k_agg(const __half* __restrict__ M,
        const int* __restrict__ cnt, const int* __restrict__ slots,
        __half* __restrict__ agg, int N)
{
    int gid  = blockIdx.x*256 + threadIdx.x;
    int node = gid >> 6;
    if (node >= N) return;
    int lane = gid & 63;
    int sub  = lane >> 3;    // which edge within group of 8
    int fl   = lane & 7;     // uint4 (8-half) column group index
    int deg = cnt[node]; deg = deg < CAP ? deg : CAP;
    const int* row = slots + (size_t)node*CAP;
    float acc[8];
    #pragma unroll
    for (int i = 0; i < 8; i++) acc[i] = 0.f;
    for (int k = sub; k < deg; k += 8){
        int s = row[k];
        float v[8];
        load_half8(M + (size_t)s*D + fl*8, v);
        #pragma unroll
        for (int i = 0; i < 8; i++) acc[i] += v[i];
    }
    #pragma unroll
    for (int i = 0; i < 8; i++){
        acc[i] += __shfl_xor(acc[i], 8);
        acc[i] += __shfl_xor(acc[i], 16);
        acc[i] += __shfl_xor(acc[i], 32);
    }
    if (sub == 0) store_half8(agg + (size_t)node*D + fl*8, acc);
}

// ================= fused update-MLP + message-MLP via MFMA =================
// 4 waves/block, each wave = 16-node M-tile x 2 tiles (block covers 128 nodes).
// A-frag: row = l&15, k = 8*(l>>4)+i.  D-frag: col = l&15, row = 4*(l>>4)+r.

__global__ void __launch_bounds__(256) k_mlp_um(const __half* __restrict__ agg,
        const float* __restrict__ wu1, const float* __restrict__ bu1,
        const float* __restrict__ wu2, const float* __restrict__ bu2,
        const float* __restrict__ wm1, const float* __restrict__ bm1,
        const float* __restrict__ wm2, const float* __restrict__ bm2,
        __half* __restrict__ y, int N)
{
    __shared__ float  lds_h [4][16][20];
    __shared__ float  lds_y [4][16][68];
    __shared__ float  lds_hm[4][16][36];
    __shared__ __half lds_m [4][16][72];

    int t  = threadIdx.x;
    int wv = t >> 6, l = t & 63;
    int m  = l & 15, g = l >> 4;

    // ---- B fragments (weights), loaded once per wave ----
    f16x8 Bu1[2], Bu2[4], Bm1[2][2], Bm2[4];
    #pragma unroll
    for (int kt = 0; kt < 2; kt++)
        #pragma unroll
        for (int i = 0; i < 8; i++)
            Bu1[kt][i] = (_Float16)wu1[(kt*32 + 8*g + i)*16 + m];
    #pragma unroll
    for (int jb = 0; jb < 4; jb++)
        #pragma unroll
        for (int i = 0; i < 8; i++){
            int k = 8*g + i;
            Bu2[jb][i] = (k < 16) ? (_Float16)wu2[k*64 + jb*16 + m] : (_Float16)0.f;
        }
    #pragma unroll
    for (int kt = 0; kt < 2; kt++)
        #pragma unroll
        for (int nt = 0; nt < 2; nt++)
            #pragma unroll
            for (int i = 0; i < 8; i++)
                Bm1[kt][nt][i] = (_Float16)wm1[(kt*32 + 8*g + i)*32 + nt*16 + m];
    #pragma unroll
    for (int jb = 0; jb < 4; jb++)
        #pragma unroll
        for (int i = 0; i < 8; i++)
            Bm2[jb][i] = (_Float16)wm2[(8*g + i)*64 + jb*16 + m];

    float bu1v = bu1[m];
    float bu2v[4], bm2v[4], bm1v[2];
    #pragma unroll
    for (int jb = 0; jb < 4; jb++){ bu2v[jb] = bu2[jb*16 + m]; bm2v[jb] = bm2[jb*16 + m]; }
    #pragma unroll
    for (int nt = 0; nt < 2; nt++) bm1v[nt] = bm1[nt*16 + m];

    #pragma unroll
    for (int tile = 0; tile < 2; tile++){
        int nb = blockIdx.x*128 + tile*64 + wv*16;
        if (nb >= N) break;

        int an = nb + m; if (an >= N) an = N - 1;
        const __half* arow = agg + (size_t)an*64;
        f16x8 Ax0 = *reinterpret_cast<const f16x8*>(arow + 8*g);
        f16x8 Ax1 = *reinterpret_cast<const f16x8*>(arow + 32 + 8*g);

        // u1
        f32x4 acc = {0.f, 0.f, 0.f, 0.f};
        acc = __builtin_amdgcn_mfma_f32_16x16x32_f16(Ax0, Bu1[0], acc, 0, 0, 0);
        acc = __builtin_amdgcn_mfma_f32_16x16x32_f16(Ax1, Bu1[1], acc, 0, 0, 0);
        #pragma unroll
        for (int r = 0; r < 4; r++)
            lds_h[wv][4*g + r][m] = fmaxf(acc[r] + bu1v, 0.f);

        f16x8 Ah;
        #pragma unroll
        for (int i = 0; i < 8; i++){
            int k = 8*g + i;
            Ah[i] = (k < 16) ? (_Float16)lds_h[wv][m][k] : (_Float16)0.f;
        }

        // u2
        #pragma unroll
        for (int jb = 0; jb < 4; jb++){
            f32x4 a2 = {0.f, 0.f, 0.f, 0.f};
            a2 = __builtin_amdgcn_mfma_f32_16x16x32_f16(Ah, Bu2[jb], a2, 0, 0, 0);
            #pragma unroll
            for (int r = 0; r < 4; r++)
                lds_y[wv][4*g + r][jb*16 + m] = fmaxf(a2[r] + bu2v[jb], 0.f);
        }

        f16x8 Ay0, Ay1;
        #pragma unroll
        for (int i = 0; i < 8; i++){
            Ay0[i] = (_Float16)lds_y[wv][m][8*g + i];
            Ay1[i] = (_Float16)lds_y[wv][m][32 + 8*g + i];
        }

        // m1
        #pragma unroll
        for (int nt = 0; nt < 2; nt++){
            f32x4 a3 = {0.f, 0.f, 0.f, 0.f};
            a3 = __builtin_amdgcn_mfma_f32_16x16x32_f16(Ay0, Bm1[0][nt], a3, 0, 0, 0);
            a3 = __builtin_amdgcn_mfma_f32_16x16x32_f16(Ay1, Bm1[1][nt], a3, 0, 0, 0);
            #pragma unroll
            for (int r = 0; r < 4; r++)
                lds_hm[wv][4*g + r][nt*16 + m] = fmaxf(a3[r] + bm1v[nt], 0.f);
        }

        f16x8 Ahm;
        #pragma unroll
        for (int i = 0; i < 8; i++)
            Ahm[i] = (_Float16)lds_hm[wv][m][8*g + i];

        // m2
        #pragma unroll
        for (int jb = 0; jb < 4; jb++){
            f32x4 a4 = {0.f, 0.f, 0.f, 0.f};
            a4 = __builtin_amdgcn_mfma_f32_16x16x32_f16(Ahm, Bm2[jb], a4, 0, 0, 0);
            #pragma unroll
            for (int r = 0; r < 4; r++)
                lds_m[wv][4*g + r][jb*16 + m] = __float2half(fmaxf(a4[r] + bm2v[jb], 0.f));
        }

        // coalesced writeback: 16 rows x 128 B
        int lr = l >> 2;
        int node = nb + lr;
        if (node < N){
            uint4* dst = (uint4*)(y + (size_t)node*64);
            const uint4* src = (const uint4*)&lds_m[wv][lr][0];
            int c = l & 3;
            dst[c]     = src[c];
            dst[c + 4] = src[c + 4];
        }
    }
}

// ================= fused update-MLP + output head via MFMA =================

__device__ inline float fast_tanh(float x){
    float ax = fabsf(x);
    float e  = __expf(2.f*ax);
    float t  = 1.f - 2.f/(e + 1.f);
    return copysignf(t, x);
}

__global__ void __launch_bounds__(256) k_mlp_uo(const __half* __restrict__ agg,
        const float* __restrict__ wu1, const float* __restrict__ bu1,
        const float* __restrict__ wu2, const float* __restrict__ bu2,
        const float* __restrict__ wo,  const float* __restrict__ bo,
        float* __restrict__ out, int N)
{
    __shared__ float lds_h[4][16][20];
    __shared__ float lds_y[4][16][68];
    __shared__ float lds_o[4][16][68];

    int t  = threadIdx.x;
    int wv = t >> 6, l = t & 63;
    int m  = l & 15, g = l >> 4;

    // ---- B fragments ----
    f16x8 Bu1[2], Bu2[4], Bo[2][4];
    #pragma unroll
    for (int kt = 0; kt < 2; kt++)
        #pragma unroll
        for (int i = 0; i < 8; i++)
            Bu1[kt][i] = (_Float16)wu1[(kt*32 + 8*g + i)*16 + m];
    #pragma unroll
    for (int jb = 0; jb < 4; jb++)
        #pragma unroll
        for (int i = 0; i < 8; i++){
            int k = 8*g + i;
            Bu2[jb][i] = (k < 16) ? (_Float16)wu2[k*64 + jb*16 + m] : (_Float16)0.f;
        }
    #pragma unroll
    for (int kt = 0; kt < 2; kt++)
        #pragma unroll
        for (int jb = 0; jb < 4; jb++)
            #pragma unroll
            for (int i = 0; i < 8; i++)
                Bo[kt][jb][i] = (_Float16)wo[(kt*32 + 8*g + i)*64 + jb*16 + m];

    float bu1v = bu1[m];
    float bu2v[4], bov[4];
    #pragma unroll
    for (int jb = 0; jb < 4; jb++){ bu2v[jb] = bu2[jb*16 + m]; bov[jb] = bo[jb*16 + m]; }

    #pragma unroll
    for (int tile = 0; tile < 2; tile++){
        int nb = blockIdx.x*128 + tile*64 + wv*16;
        if (nb >= N) break;

        int an = nb + m; if (an >= N) an = N - 1;
        const __half* arow = agg + (size_t)an*64;
        f16x8 Ax0 = *reinterpret_cast<const f16x8*>(arow + 8*g);
        f16x8 Ax1 = *reinterpret_cast<const f16x8*>(arow + 32 + 8*g);

        // u1
        f32x4 acc = {0.f, 0.f, 0.f, 0.f};
        acc = __builtin_amdgcn_mfma_f32_16x16x32_f16(Ax0, Bu1[0], acc, 0, 0, 0);
        acc = __builtin_amdgcn_mfma_f32_16x16x32_f16(Ax1, Bu1[1], acc, 0, 0, 0);
        #pragma unroll
        for (int r = 0; r < 4; r++)
            lds_h[wv][4*g + r][m] = fmaxf(acc[r] + bu1v, 0.f);

        f16x8 Ah;
        #pragma unroll
        for (int i = 0; i < 8; i++){
            int k = 8*g + i;
            Ah[i] = (k < 16) ? (_Float16)lds_h[wv][m][k] : (_Float16)0.f;
        }

        // u2
        #pragma unroll
        for (int jb = 0; jb < 4; jb++){
            f32x4 a2 = {0.f, 0.f, 0.f, 0.f};
            a2 = __builtin_amdgcn_mfma_f32_16x16x32_f16(Ah, Bu2[jb], a2, 0, 0, 0);
            #pragma unroll
            for (int r = 0; r < 4; r++)
                lds_y[wv][4*g + r][jb*16 + m] = fmaxf(a2[r] + bu2v[jb], 0.f);
        }

        f16x8 Ay0, Ay1;
        #pragma unroll
        for (int i = 0; i < 8; i++){
            Ay0[i] = (_Float16)lds_y[wv][m][8*g + i];
            Ay1[i] = (_Float16)lds_y[wv][m][32 + 8*g + i];
        }

        // head
        #pragma unroll
        for (int jb = 0; jb < 4; jb++){
            f32x4 a3 = {0.f, 0.f, 0.f, 0.f};
            a3 = __builtin_amdgcn_mfma_f32_16x16x32_f16(Ay0, Bo[0][jb], a3, 0, 0, 0);
            a3 = __builtin_amdgcn_mfma_f32_16x16x32_f16(Ay1, Bo[1][jb], a3, 0, 0, 0);
            #pragma unroll
            for (int r = 0; r < 4; r++)
                lds_o[wv][4*g + r][jb*16 + m] = fast_tanh(a3[r] + bov[jb]);
        }

        // coalesced writeback: 16 rows x 256 B
        int lr = l >> 2;
        int node = nb + lr;
        if (node < N){
            float4* dst = (float4*)(out + (size_t)node*64);
            const float4* src = (const float4*)&lds_o[wv][lr][0];
            int c = l & 3;
            dst[c]      = src[c];
            dst[c + 4]  = src[c + 4];
            dst[c + 8]  = src[c + 8];
            dst[c + 12] = src[c + 12];
        }
    }
}

// ================= launch =================

extern "C" void kernel_launch(void* const* d_in, const int* in_sizes, int n_in,
                              void* d_out, int out_size, void* d_ws, size_t ws_size,
                              hipStream_t stream)
{
    const float* x_interfered = (const float*)d_in[1];
    const int*   e_s2i        = (const int*)d_in[2];
    const int*   e_i2s        = (const int*)d_in[3];
    const float* wm1 = (const float*)d_in[4];  const float* bm1 = (const float*)d_in[5];
    const float* wm2 = (const float*)d_in[6];  const float* bm2 = (const float*)d_in[7];
    const float* wu1 = (const float*)d_in[8];  const float* bu1 = (const float*)d_in[9];
    const float* wu2 = (const float*)d_in[10]; const float* bu2 = (const float*)d_in[11];
    const float* wo  = (const float*)d_in[12]; const float* bo  = (const float*)d_in[13];

    const int NS = in_sizes[0] / D;
    const int NI = in_sizes[1] / D;
    const int E  = in_sizes[2] / 2;
    const int NMAX = (NS > NI) ? NS : NI;
    const int NTOT = NI + NS;   // rows [0,NI)=dst interfered, [NI,NTOT)=dst served

    const int NBUK = ((NTOT - 1) >> 8) + 1;          // RPB=256 rows per bucket
    int avg = (2*E) / NBUK;
    const int BSTRIDE = ((2*avg) + 1023) & ~1023;    // 2x average, safe for Binomial spread

    char* p = (char*)d_ws;
    auto alloc = [&](size_t bytes) -> void* {
        void* r = (void*)p;
        p += (bytes + 255) & ~(size_t)255;
        return r;
    };
    __half*   M      = (__half*)alloc((size_t)NMAX*D*2);
    __half*   AGG    = (__half*)alloc((size_t)NMAX*D*2);
    int*      cnt    = (int*)alloc((size_t)NTOT*4);
    int*      gcur   = (int*)alloc((size_t)NBUK*4);
    int*      slots  = (int*)alloc((size_t)NTOT*CAP*4);
    unsigned* buckets= (unsigned*)alloc((size_t)NBUK*BSTRIDE*4);
    (void)ws_size; (void)n_in; (void)out_size;

    const int* cnt_i = cnt;
    const int* cnt_s = cnt + NI;
    const int* slots_i = slots;
    const int* slots_s = slots + (size_t)NI*CAP;

    // custom zero kernel (graph-capture-safe)
    k_zero<<<1, 256, 0, stream>>>(gcur, NBUK);

    const int nbEdge = (2*E + EPB - 1)/EPB;
    const int nbMlp  = (NI + 511)/512;
    // Phase A: bucket both relations' edges + mlp_m(x_interfered) -> M (fp16)
    k_bucket_mlpm<<<nbEdge + nbMlp, 512, 0, stream>>>(
        e_s2i, e_i2s, E, NI, NBUK, BSTRIDE, gcur, buckets,
        x_interfered, wm1, bm1, wm2, bm2, M, NI, nbEdge);
    // Phase B: LDS-assembled scatter, one block per bucket
    k_scatter_lds<<<NBUK, 512, 0, stream>>>(gcur, buckets, BSTRIDE, NTOT, cnt, slots);

    // live chain: i0 -> s1 -> i2 -> s3 -> out  (single M buffer, fully consumed before rewrite)
    // conv1 (i2s): s1 = U(sum M(i0))
    k_agg<<<((size_t)NS*64 + 255)/256, 256, 0, stream>>>(M, cnt_s, slots_s, AGG, NS);
    k_mlp_um<<<(NS + 127)/128, 256, 0, stream>>>(AGG, wu1, bu1, wu2, bu2,
                                               wm1, bm1, wm2, bm2, M, NS);
    // conv2 (s2i): i2 = U(sum M(s1))
    k_agg<<<((size_t)NI*64 + 255)/256, 256, 0, stream>>>(M, cnt_i, slots_i, AGG, NI);
    k_mlp_um<<<(NI + 127)/128, 256, 0, stream>>>(AGG, wu1, bu1, wu2, bu2,
                                               wm1, bm1, wm2, bm2, M, NI);
    // conv3 (i2s): s3 = U(sum M(i2)); fused with output head
    k_agg<<<((size_t)NS*64 + 255)/256, 256, 0, stream>>>(M, cnt_s, slots_s, AGG, NS);
    k_mlp_uo<<<(NS + 127)/128, 256, 0, stream>>>(AGG, wu1, bu1, wu2, bu2,
                                               wo, bo, (float*)d_out, NS);
}